// Round 4
// baseline (266.080 us; speedup 1.0000x reference)
//
#include <hip/hip_runtime.h>
#include <math.h>

#define BATCH 16
#define NCLS 80
#define TOPK 100
#define NBOX 22743
#define NSLOT (NCLS*TOPK)   // 8000 per image
#define TPAD 22752          // padded (s,a)-major total per image
#define NQ4 5688            // TPAD/4 quads per image
#define NCH 8               // chunks per image scan
#define QCH 711             // NQ4/NCH
#define CAP 1024

__device__ __forceinline__ float sigf(float x){ return 1.0f/(1.0f + expf(-x)); }

// quad geometry: i in [0,5688) -> scale/anchor/pixel (branch w/ const divisors, no tables)
struct QGeo { const float* f; int a; int p; int P; int conf_off; int nb; bool tail; };
__device__ __forceinline__ QGeo qgeo(int i, const float* f0, const float* f1, const float* f2){
    QGeo g;
    if (i < 273){        int l=i;      g.a=l/91;   int lq=l-g.a*91;   g.P=361;  g.f=f0; g.conf_off=g.a*364      + lq*4; g.nb=g.a;      g.p=lq*4; g.tail=(lq==90); }
    else if (i < 1356){  int l=i-273;  g.a=l/361;  int lq=l-g.a*361;  g.P=1444; g.f=f1; g.conf_off=1092+g.a*1444+ lq*4; g.nb=1083+g.a; g.p=lq*4; g.tail=false; }
    else {               int l=i-1356; g.a=l/1444; int lq=l-g.a*1444; g.P=5776; g.f=f2; g.conf_off=5424+g.a*5776+ lq*4; g.nb=5415+g.a; g.p=lq*4; g.tail=false; }
    return g;
}

// ---------------- zero scratch (ghist + gcnt contiguous) ----------------
__global__ __launch_bounds__(256)
void zero_kernel(unsigned int* __restrict__ p, int n){
    int i = blockIdx.x*256 + threadIdx.x;
    if (i < n) p[i] = 0u;
}

// ---------------- decode: boxes + conf (padded (s,a)-major) ----------------
__global__ __launch_bounds__(256)
void decode_kernel(const float* __restrict__ f0, const float* __restrict__ f1,
                   const float* __restrict__ f2, const float* __restrict__ anchors,
                   const float* __restrict__ ishape,
                   float* __restrict__ boxes, float* __restrict__ conf2)
{
    int r = blockIdx.x*blockDim.x + threadIdx.x;
    int b = blockIdx.y;
    if (r >= TPAD) return;
    int sa, p;
    if (r < 1092){ sa = r/364; p = r - sa*364; }
    else if (r < 5424){ int q = r-1092; sa = 3 + q/1444; p = q - (sa-3)*1444; }
    else { int q = r-5424; sa = 6 + q/5776; p = q - (sa-6)*5776; }
    int s = (sa>=6)?2:((sa>=3)?1:0);
    int a = sa - 3*s;
    const float* f; int P, G, off, abase;
    if (s==0){ f=f0; P=361;  G=19; off=0;    abase=6; }
    else if (s==1){ f=f1; P=1444; G=38; off=1083; abase=3; }
    else        { f=f2; P=5776; G=76; off=5415; abase=0; }
    size_t cidx = (size_t)b*TPAD + r;
    if (p >= P){ conf2[cidx] = 0.0f; return; }

    const float* fb = f + ((size_t)b*255 + a*85)*(size_t)P;
    float tx = fb[(size_t)0*P + p];
    float ty = fb[(size_t)1*P + p];
    float tw = fb[(size_t)2*P + p];
    float th = fb[(size_t)3*P + p];
    float tc = fb[(size_t)4*P + p];
    int yy = p / G, xx = p - yy*G;
    float g = (float)G;
    float aw = anchors[(abase+a)*2+0];
    float ah = anchors[(abase+a)*2+1];
    float xn = (sigf(tx) + (float)xx) / g;
    float yn = (sigf(ty) + (float)yy) / g;
    float wn = aw * expf(tw) / 608.0f;
    float hn = ah * expf(th) / 608.0f;
    float ih = ishape[0], iw = ishape[1];
    float m  = fminf(608.0f/ih, 608.0f/iw);
    float nh = rintf(ih*m), nw = rintf(iw*m);
    float offy = (608.0f - nh) / 2.0f / 608.0f;
    float offx = (608.0f - nw) / 2.0f / 608.0f;
    float scy = 608.0f/nh, scx = 608.0f/nw;
    float y = (yn - offy)*scy;
    float x = (xn - offx)*scx;
    float hh = hn*scy, ww = wn*scx;
    int n = off + p*3 + a;
    size_t o = ((size_t)b*NBOX + n)*4;
    boxes[o+0] = (y - hh/2.0f)*ih;
    boxes[o+1] = (x - ww/2.0f)*iw;
    boxes[o+2] = (y + hh/2.0f)*ih;
    boxes[o+3] = (x + ww/2.0f)*iw;

    conf2[cidx] = sigf(tc);
}

#define BIN_OF(sc) ({ int _b = (int)(__float_as_uint(sc)>>16) - 0x3E99; _b < 0 ? 0 : (_b > 255 ? 255 : _b); })

// ---------------- histogram pass: 4 classes/block, chunked boxes ------------
__global__ __launch_bounds__(256)
void hist_kernel(const float* __restrict__ f0, const float* __restrict__ f1,
                 const float* __restrict__ f2, const float* __restrict__ conf2,
                 unsigned int* __restrict__ ghist)
{
    int cg = blockIdx.x, b = blockIdx.y, z = blockIdx.z, tid = threadIdx.x;
    int c0 = cg*4;
    __shared__ unsigned int h[4][256];
    h[0][tid]=0; h[1][tid]=0; h[2][tid]=0; h[3][tid]=0;
    __syncthreads();
    int iend = (z+1)*QCH;
    for (int i = z*QCH + tid; i < iend; i += 256){
        QGeo g = qgeo(i, f0, f1, f2);
        float4 c4 = *(const float4*)(conf2 + (size_t)b*TPAD + g.conf_off);
        const float* pr = g.f + ((size_t)b*255 + g.a*85 + 5 + c0)*(size_t)g.P + g.p;
#pragma unroll
        for (int cls=0; cls<4; cls++){
            float p0,p1,p2,p3;
            if (!g.tail){
                float4 t = *(const float4*)pr;
                p0=t.x; p1=t.y; p2=t.z; p3=t.w;
            } else {
                p0 = pr[0]; p1 = -INFINITY; p2 = -INFINITY; p3 = -INFINITY;
            }
            float s0 = c4.x*sigf(p0), s1 = c4.y*sigf(p1), s2 = c4.z*sigf(p2), s3 = c4.w*sigf(p3);
            if (s0 > 0.3f) atomicAdd(&h[cls][BIN_OF(s0)], 1u);
            if (s1 > 0.3f) atomicAdd(&h[cls][BIN_OF(s1)], 1u);
            if (s2 > 0.3f) atomicAdd(&h[cls][BIN_OF(s2)], 1u);
            if (s3 > 0.3f) atomicAdd(&h[cls][BIN_OF(s3)], 1u);
            pr += g.P;
        }
    }
    __syncthreads();
    size_t hb = ((size_t)b*NCLS + c0)*256 + tid;
    if (h[0][tid]) atomicAdd(&ghist[hb      ], h[0][tid]);
    if (h[1][tid]) atomicAdd(&ghist[hb + 256], h[1][tid]);
    if (h[2][tid]) atomicAdd(&ghist[hb + 512], h[2][tid]);
    if (h[3][tid]) atomicAdd(&ghist[hb + 768], h[3][tid]);
}

// ---------------- threshold-bin per (b,c) ----------------
__global__ __launch_bounds__(256)
void tb_kernel(const unsigned int* __restrict__ ghist, int* __restrict__ tb)
{
    int bc = blockIdx.x, tid = threadIdx.x;
    __shared__ int sufA[256], sufB[256];
    __shared__ int TbS;
    if (tid == 0) TbS = 0;
    sufA[tid] = (int)ghist[(size_t)bc*256 + tid];
    __syncthreads();
    int* cur = sufA; int* nxt = sufB;
    for (int d=1; d<256; d<<=1){
        int v = cur[tid] + ((tid+d) < 256 ? cur[tid+d] : 0);
        nxt[tid] = v;
        __syncthreads();
        int* t_ = cur; cur = nxt; nxt = t_;
    }
    if (cur[tid] >= TOPK && (tid == 255 || cur[tid+1] < TOPK)) TbS = tid;
    __syncthreads();
    if (tid == 0) tb[bc] = TbS;
}

// ---------------- compact pass: candidates (bin >= Tb) to global ------------
__global__ __launch_bounds__(256)
void compact_kernel(const float* __restrict__ f0, const float* __restrict__ f1,
                    const float* __restrict__ f2, const float* __restrict__ conf2,
                    const int* __restrict__ tb, int* __restrict__ gcnt,
                    float* __restrict__ gsc, int* __restrict__ gix)
{
    int cg = blockIdx.x, b = blockIdx.y, z = blockIdx.z, tid = threadIdx.x;
    int c0 = cg*4;
    int bc0 = b*NCLS + c0;
    int t0 = tb[bc0], t1 = tb[bc0+1], t2 = tb[bc0+2], t3 = tb[bc0+3];
    int iend = (z+1)*QCH;
    for (int i = z*QCH + tid; i < iend; i += 256){
        QGeo g = qgeo(i, f0, f1, f2);
        float4 c4 = *(const float4*)(conf2 + (size_t)b*TPAD + g.conf_off);
        const float* pr = g.f + ((size_t)b*255 + g.a*85 + 5 + c0)*(size_t)g.P + g.p;
#pragma unroll
        for (int cls=0; cls<4; cls++){
            int tX = (cls==0)?t0:((cls==1)?t1:((cls==2)?t2:t3));
            float p0,p1,p2,p3;
            if (!g.tail){
                float4 t = *(const float4*)pr;
                p0=t.x; p1=t.y; p2=t.z; p3=t.w;
            } else {
                p0 = pr[0]; p1 = -INFINITY; p2 = -INFINITY; p3 = -INFINITY;
            }
#define DOJ(J, PR, CC) { float sc = (CC)*sigf(PR); \
            if (sc > 0.3f){ int bin = BIN_OF(sc); \
                if (bin >= tX){ \
                    int pos = atomicAdd(&gcnt[bc0+cls], 1); \
                    if (pos < CAP){ \
                        gsc[(size_t)(bc0+cls)*CAP + pos] = sc; \
                        gix[(size_t)(bc0+cls)*CAP + pos] = g.nb + 3*(g.p+J); } } } }
            DOJ(0,p0,c4.x) DOJ(1,p1,c4.y) DOJ(2,p2,c4.z) DOJ(3,p3,c4.w)
#undef DOJ
            pr += g.P;
        }
    }
}

// ---------------- per-(b,c): sort candidates + NMS + write out --------------
__global__ __launch_bounds__(256)
void sortnms_kernel(const float* __restrict__ gsc, const int* __restrict__ gix,
                    const int* __restrict__ gcnt, const float* __restrict__ boxes,
                    float* __restrict__ out)
{
    int c = blockIdx.x, b = blockIdx.y, tid = threadIdx.x;
    int bc = b*NCLS + c;
    __shared__ float cs[CAP];
    __shared__ int   ci[CAP];
    int n = gcnt[bc]; if (n > CAP) n = CAP;
    for (int t=tid; t<CAP; t+=256){
        if (t < n){ cs[t] = gsc[(size_t)bc*CAP + t]; ci[t] = gix[(size_t)bc*CAP + t]; }
        else { cs[t] = -INFINITY; ci[t] = 0x7FFFFFFF; }
    }
    __syncthreads();
    int S = 128; while (S < n) S <<= 1;
    for (int k=2; k<=S; k<<=1){
        for (int j=k>>1; j>0; j>>=1){
            for (int t=tid; t<S; t+=256){
                int ixj = t ^ j;
                if (ixj > t){
                    float s1 = cs[t], s2 = cs[ixj];
                    int   i1 = ci[t], i2 = ci[ixj];
                    bool b2_first = (s2 > s1) || (s2 == s1 && i2 < i1);
                    bool b1_first = (s1 > s2) || (s1 == s2 && i1 < i2);
                    bool desc = ((t & k) == 0);
                    bool sw = desc ? b2_first : b1_first;
                    if (sw){ cs[t]=s2; cs[ixj]=s1; ci[t]=i2; ci[ixj]=i1; }
                }
            }
            __syncthreads();
        }
    }

    // NMS on wave 0 (shfl broadcast, no barriers)
    int w = tid >> 6, lane = tid & 63;
    if (w == 0){
        int o0 = bc*TOPK;
        int nn = n < TOPK ? n : TOPK;
        float ay1=0.f,ax1=0.f,ay2=0.f,ax2=0.f,aar=0.f,asc=0.f; int ak=0;
        float by1=0.f,bx1=0.f,by2=0.f,bx2=0.f,bar_=0.f,bsc=0.f; int bk=0;
        {
            float s = cs[lane];
            if (s > 0.3f){
                asc = s;
                size_t q = ((size_t)b*NBOX + ci[lane])*4;
                ay1=boxes[q]; ax1=boxes[q+1]; ay2=boxes[q+2]; ax2=boxes[q+3]; ak=1;
            }
            aar = (ay2-ay1)*(ax2-ax1);
        }
        if (lane + 64 < TOPK){
            float s = cs[lane+64];
            if (s > 0.3f){
                bsc = s;
                size_t q = ((size_t)b*NBOX + ci[lane+64])*4;
                by1=boxes[q]; bx1=boxes[q+1]; by2=boxes[q+2]; bx2=boxes[q+3]; bk=1;
            }
            bar_ = (by2-by1)*(bx2-bx1);
        }
        for (int i=0; i<nn; i++){
            float iy1,ix1,iy2,ix2,iar; int ik;
            if (i < 64){
                iy1=__shfl(ay1,i); ix1=__shfl(ax1,i); iy2=__shfl(ay2,i); ix2=__shfl(ax2,i);
                iar=__shfl(aar,i); ik=__shfl(ak,i);
            } else {
                int l = i - 64;
                iy1=__shfl(by1,l); ix1=__shfl(bx1,l); iy2=__shfl(by2,l); ix2=__shfl(bx2,l);
                iar=__shfl(bar_,l); ik=__shfl(bk,l);
            }
            if (ik){
                if (ak && lane > i){
                    float q1=fmaxf(iy1,ay1), q2=fmaxf(ix1,ax1);
                    float q3=fminf(iy2,ay2), q4=fminf(ix2,ax2);
                    float inter = fmaxf(q3-q1,0.0f)*fmaxf(q4-q2,0.0f);
                    float iou = inter/(iar + aar - inter + 1e-9f);
                    if (iou > 0.3f) ak = 0;
                }
                if (bk && lane + 64 > i){
                    float q1=fmaxf(iy1,by1), q2=fmaxf(ix1,bx1);
                    float q3=fminf(iy2,by2), q4=fminf(ix2,bx2);
                    float inter = fmaxf(q3-q1,0.0f)*fmaxf(q4-q2,0.0f);
                    float iou = inter/(iar + bar_ - inter + 1e-9f);
                    if (iou > 0.3f) bk = 0;
                }
            }
        }
        {
            float k = ak ? 1.0f : 0.0f;
            size_t o5 = ((size_t)(o0+lane))*5;
            out[o5+0]=ay1*k; out[o5+1]=ax1*k; out[o5+2]=ay2*k; out[o5+3]=ax2*k; out[o5+4]=asc*k;
        }
        if (lane + 64 < TOPK){
            float k = bk ? 1.0f : 0.0f;
            size_t o5 = ((size_t)(o0+lane+64))*5;
            out[o5+0]=by1*k; out[o5+1]=bx1*k; out[o5+2]=by2*k; out[o5+3]=bx2*k; out[o5+4]=bsc*k;
        }
    }
}

// -------- per-image top-50 cap: compact positives, then 50 extractions ------
__global__ __launch_bounds__(1024)
void cap_kernel(float* __restrict__ out)
{
    int b = blockIdx.x, tid = threadIdx.x;
    int lane = tid & 63, w = tid >> 6;
    __shared__ float ls[NSLOT];
    __shared__ unsigned short li[NSLOT];
    __shared__ unsigned char sel[NSLOT];
    __shared__ int m;
    __shared__ float wrv[16];
    __shared__ int   wri[16], wrp[16];
    if (tid == 0) m = 0;
    __syncthreads();
    for (int u=tid; u<NSLOT; u+=1024){
        float v = out[((size_t)b*NSLOT + u)*5 + 4];
        if (v > 0.0f){
            int pos = atomicAdd(&m, 1);
            ls[pos] = v; li[pos] = (unsigned short)u;
        }
    }
    __syncthreads();
    int mm = m;
    if (mm <= 50) return;   // all positives kept; zero rows already zero
    for (int i=tid; i<mm; i+=1024) sel[i] = 0;
    __syncthreads();
    for (int it=0; it<50; it++){
        float bv = -INFINITY; int bi = 0x7FFFFFFF; int bp = -1;
        for (int i=tid; i<mm; i+=1024){
            float v = ls[i]; int u = li[i];
            if (v > bv || (v == bv && u < bi)){ bv = v; bi = u; bp = i; }
        }
        for (int off=32; off; off>>=1){
            float v2 = __shfl_xor(bv, off); int i2 = __shfl_xor(bi, off); int p2 = __shfl_xor(bp, off);
            if (v2 > bv || (v2 == bv && i2 < bi)){ bv = v2; bi = i2; bp = p2; }
        }
        if (lane == 0){ wrv[w] = bv; wri[w] = bi; wrp[w] = bp; }
        __syncthreads();
        if (w == 0){
            float v = (lane < 16) ? wrv[lane] : -INFINITY;
            int   i = (lane < 16) ? wri[lane] : 0x7FFFFFFF;
            int   p = (lane < 16) ? wrp[lane] : -1;
            for (int off=8; off; off>>=1){
                float v2 = __shfl_xor(v, off); int i2 = __shfl_xor(i, off); int p2 = __shfl_xor(p, off);
                if (v2 > v || (v2 == v && i2 < i)){ v = v2; i = i2; p = p2; }
            }
            if (lane == 0){ sel[p] = 1; ls[p] = -INFINITY; }
        }
        __syncthreads();
    }
    for (int i=tid; i<mm; i+=1024){
        if (!sel[i]){
            size_t o5 = ((size_t)b*NSLOT + li[i])*5;
            out[o5+0]=0.f; out[o5+1]=0.f; out[o5+2]=0.f; out[o5+3]=0.f; out[o5+4]=0.f;
        }
    }
}

extern "C" void kernel_launch(void* const* d_in, const int* in_sizes, int n_in,
                              void* d_out, int out_size, void* d_ws, size_t ws_size,
                              hipStream_t stream)
{
    const float* f0 = (const float*)d_in[0];
    const float* f1 = (const float*)d_in[1];
    const float* f2 = (const float*)d_in[2];
    const float* anchors = (const float*)d_in[3];
    const float* ishape  = (const float*)d_in[4];
    float* out = (float*)d_out;

    float* boxes = (float*)d_ws;                                   // 16*22743*4
    float* conf2 = boxes + (size_t)BATCH*NBOX*4;                   // 16*22752
    unsigned int* ghist = (unsigned int*)(conf2 + (size_t)BATCH*TPAD); // 1280*256
    int* gcnt = (int*)(ghist + (size_t)BATCH*NCLS*256);            // 1280 (contiguous after ghist)
    int* tb   = gcnt + BATCH*NCLS;                                 // 1280
    float* gsc = (float*)(tb + BATCH*NCLS);                        // 1280*1024
    int*   gix = (int*)(gsc + (size_t)BATCH*NCLS*CAP);             // 1280*1024

    const int nzero = BATCH*NCLS*256 + BATCH*NCLS;                 // ghist + gcnt
    zero_kernel<<<(nzero + 255)/256, 256, 0, stream>>>(ghist, nzero);

    dim3 dgrid((TPAD + 255)/256, BATCH);
    decode_kernel<<<dgrid, 256, 0, stream>>>(f0, f1, f2, anchors, ishape, boxes, conf2);

    dim3 hgrid(NCLS/4, BATCH, NCH);
    hist_kernel<<<hgrid, 256, 0, stream>>>(f0, f1, f2, conf2, ghist);

    tb_kernel<<<BATCH*NCLS, 256, 0, stream>>>(ghist, tb);

    compact_kernel<<<hgrid, 256, 0, stream>>>(f0, f1, f2, conf2, tb, gcnt, gsc, gix);

    dim3 sgrid(NCLS, BATCH);
    sortnms_kernel<<<sgrid, 256, 0, stream>>>(gsc, gix, gcnt, boxes, out);

    cap_kernel<<<BATCH, 1024, 0, stream>>>(out);
}

// Round 5
// 148.002 us; speedup vs baseline: 1.7978x; 1.7978x over previous
//
#include <hip/hip_runtime.h>
#include <math.h>

#define BATCH 16
#define NCLS 80
#define TOPK 100
#define NBOX 22743
#define NSLOT (NCLS*TOPK)   // 8000 per image
#define TPAD 22752          // padded (s,a)-major total per image
#define NQ4 5688            // TPAD/4 quads per image
#define NCH 8               // chunks per image scan
#define QCH 711             // NQ4/NCH
#define CAP 1024
#define NZERO (BATCH*NCLS*256 + BATCH*NCLS)   // ghist + gcnt words

__device__ __forceinline__ float sigf(float x){ return 1.0f/(1.0f + expf(-x)); }

#define BIN_OF(sc) ({ int _b = (int)(__float_as_uint(sc)>>16) - 0x3E99; _b < 0 ? 0 : (_b > 255 ? 255 : _b); })

// quad geometry: i in [0,5688) -> scale/anchor/pixel (branch w/ const divisors)
struct QGeo { const float* f; int a; int p; int P; int conf_off; int nb; bool tail; };
__device__ __forceinline__ QGeo qgeo(int i, const float* f0, const float* f1, const float* f2){
    QGeo g;
    if (i < 273){        int l=i;      g.a=l/91;   int lq=l-g.a*91;   g.P=361;  g.f=f0; g.conf_off=g.a*364      + lq*4; g.nb=g.a;      g.p=lq*4; g.tail=(lq==90); }
    else if (i < 1356){  int l=i-273;  g.a=l/361;  int lq=l-g.a*361;  g.P=1444; g.f=f1; g.conf_off=1092+g.a*1444+ lq*4; g.nb=1083+g.a; g.p=lq*4; g.tail=false; }
    else {               int l=i-1356; g.a=l/1444; int lq=l-g.a*1444; g.P=5776; g.f=f2; g.conf_off=5424+g.a*5776+ lq*4; g.nb=5415+g.a; g.p=lq*4; g.tail=false; }
    return g;
}

// ------- decode: boxes + conf (padded (s,a)-major); also zeroes ghist+gcnt ----
__global__ __launch_bounds__(256)
void decode_kernel(const float* __restrict__ f0, const float* __restrict__ f1,
                   const float* __restrict__ f2, const float* __restrict__ anchors,
                   const float* __restrict__ ishape,
                   float* __restrict__ boxes, float* __restrict__ conf2,
                   unsigned int* __restrict__ gzero)
{
    int tid = threadIdx.x;
    int b = blockIdx.y;
    int r = blockIdx.x*blockDim.x + tid;
    // zero ghist+gcnt (grid-stride over whole grid, before any compute)
    int gid = (b*gridDim.x + blockIdx.x)*256 + tid;
    if (gid < NZERO) gzero[gid] = 0u;
    if (r >= TPAD) return;
    int sa, p;
    if (r < 1092){ sa = r/364; p = r - sa*364; }
    else if (r < 5424){ int q = r-1092; sa = 3 + q/1444; p = q - (sa-3)*1444; }
    else { int q = r-5424; sa = 6 + q/5776; p = q - (sa-6)*5776; }
    int s = (sa>=6)?2:((sa>=3)?1:0);
    int a = sa - 3*s;
    const float* f; int P, G, off, abase;
    if (s==0){ f=f0; P=361;  G=19; off=0;    abase=6; }
    else if (s==1){ f=f1; P=1444; G=38; off=1083; abase=3; }
    else        { f=f2; P=5776; G=76; off=5415; abase=0; }
    size_t cidx = (size_t)b*TPAD + r;
    if (p >= P){ conf2[cidx] = 0.0f; return; }

    const float* fb = f + ((size_t)b*255 + a*85)*(size_t)P;
    float tx = fb[(size_t)0*P + p];
    float ty = fb[(size_t)1*P + p];
    float tw = fb[(size_t)2*P + p];
    float th = fb[(size_t)3*P + p];
    float tc = fb[(size_t)4*P + p];
    int yy = p / G, xx = p - yy*G;
    float g = (float)G;
    float aw = anchors[(abase+a)*2+0];
    float ah = anchors[(abase+a)*2+1];
    float xn = (sigf(tx) + (float)xx) / g;
    float yn = (sigf(ty) + (float)yy) / g;
    float wn = aw * expf(tw) / 608.0f;
    float hn = ah * expf(th) / 608.0f;
    float ih = ishape[0], iw = ishape[1];
    float m  = fminf(608.0f/ih, 608.0f/iw);
    float nh = rintf(ih*m), nw = rintf(iw*m);
    float offy = (608.0f - nh) / 2.0f / 608.0f;
    float offx = (608.0f - nw) / 2.0f / 608.0f;
    float scy = 608.0f/nh, scx = 608.0f/nw;
    float y = (yn - offy)*scy;
    float x = (xn - offx)*scx;
    float hh = hn*scy, ww = wn*scx;
    int n = off + p*3 + a;
    size_t o = ((size_t)b*NBOX + n)*4;
    boxes[o+0] = (y - hh/2.0f)*ih;
    boxes[o+1] = (x - ww/2.0f)*iw;
    boxes[o+2] = (y + hh/2.0f)*ih;
    boxes[o+3] = (x + ww/2.0f)*iw;

    conf2[cidx] = sigf(tc);
}

// ---------------- histogram pass: 4 classes/block, chunked boxes ------------
__global__ __launch_bounds__(256)
void hist_kernel(const float* __restrict__ f0, const float* __restrict__ f1,
                 const float* __restrict__ f2, const float* __restrict__ conf2,
                 unsigned int* __restrict__ ghist)
{
    int cg = blockIdx.x, b = blockIdx.y, z = blockIdx.z, tid = threadIdx.x;
    int c0 = cg*4;
    __shared__ unsigned int h[4][256];
    h[0][tid]=0; h[1][tid]=0; h[2][tid]=0; h[3][tid]=0;
    __syncthreads();
    int iend = (z+1)*QCH;
    for (int i = z*QCH + tid; i < iend; i += 256){
        QGeo g = qgeo(i, f0, f1, f2);
        float4 c4 = *(const float4*)(conf2 + (size_t)b*TPAD + g.conf_off);
        const float* pr = g.f + ((size_t)b*255 + g.a*85 + 5 + c0)*(size_t)g.P + g.p;
#pragma unroll
        for (int cls=0; cls<4; cls++){
            float p0,p1,p2,p3;
            if (!g.tail){
                float4 t = *(const float4*)pr;
                p0=t.x; p1=t.y; p2=t.z; p3=t.w;
            } else {
                p0 = pr[0]; p1 = -INFINITY; p2 = -INFINITY; p3 = -INFINITY;
            }
            float s0 = c4.x*sigf(p0), s1 = c4.y*sigf(p1), s2 = c4.z*sigf(p2), s3 = c4.w*sigf(p3);
            if (s0 > 0.3f) atomicAdd(&h[cls][BIN_OF(s0)], 1u);
            if (s1 > 0.3f) atomicAdd(&h[cls][BIN_OF(s1)], 1u);
            if (s2 > 0.3f) atomicAdd(&h[cls][BIN_OF(s2)], 1u);
            if (s3 > 0.3f) atomicAdd(&h[cls][BIN_OF(s3)], 1u);
            pr += g.P;
        }
    }
    __syncthreads();
    size_t hb = ((size_t)b*NCLS + c0)*256 + tid;
    if (h[0][tid]) atomicAdd(&ghist[hb      ], h[0][tid]);
    if (h[1][tid]) atomicAdd(&ghist[hb + 256], h[1][tid]);
    if (h[2][tid]) atomicAdd(&ghist[hb + 512], h[2][tid]);
    if (h[3][tid]) atomicAdd(&ghist[hb + 768], h[3][tid]);
}

// ---------------- threshold-bin per (b,c) ----------------
__global__ __launch_bounds__(256)
void tb_kernel(const unsigned int* __restrict__ ghist, int* __restrict__ tb)
{
    int bc = blockIdx.x, tid = threadIdx.x;
    __shared__ int sufA[256], sufB[256];
    __shared__ int TbS;
    if (tid == 0) TbS = 0;
    sufA[tid] = (int)ghist[(size_t)bc*256 + tid];
    __syncthreads();
    int* cur = sufA; int* nxt = sufB;
    for (int d=1; d<256; d<<=1){
        int v = cur[tid] + ((tid+d) < 256 ? cur[tid+d] : 0);
        nxt[tid] = v;
        __syncthreads();
        int* t_ = cur; cur = nxt; nxt = t_;
    }
    if (cur[tid] >= TOPK && (tid == 255 || cur[tid+1] < TOPK)) TbS = tid;
    __syncthreads();
    if (tid == 0) tb[bc] = TbS;
}

// ---------------- compact pass: candidates (bin >= Tb) to global ------------
__global__ __launch_bounds__(256)
void compact_kernel(const float* __restrict__ f0, const float* __restrict__ f1,
                    const float* __restrict__ f2, const float* __restrict__ conf2,
                    const int* __restrict__ tb, int* __restrict__ gcnt,
                    float* __restrict__ gsc, int* __restrict__ gix)
{
    int cg = blockIdx.x, b = blockIdx.y, z = blockIdx.z, tid = threadIdx.x;
    int c0 = cg*4;
    int bc0 = b*NCLS + c0;
    int t0 = tb[bc0], t1 = tb[bc0+1], t2 = tb[bc0+2], t3 = tb[bc0+3];
    int iend = (z+1)*QCH;
    for (int i = z*QCH + tid; i < iend; i += 256){
        QGeo g = qgeo(i, f0, f1, f2);
        float4 c4 = *(const float4*)(conf2 + (size_t)b*TPAD + g.conf_off);
        const float* pr = g.f + ((size_t)b*255 + g.a*85 + 5 + c0)*(size_t)g.P + g.p;
#pragma unroll
        for (int cls=0; cls<4; cls++){
            int tX = (cls==0)?t0:((cls==1)?t1:((cls==2)?t2:t3));
            float p0,p1,p2,p3;
            if (!g.tail){
                float4 t = *(const float4*)pr;
                p0=t.x; p1=t.y; p2=t.z; p3=t.w;
            } else {
                p0 = pr[0]; p1 = -INFINITY; p2 = -INFINITY; p3 = -INFINITY;
            }
#define DOJ(J, PR, CC) { float sc = (CC)*sigf(PR); \
            if (sc > 0.3f){ int bin = BIN_OF(sc); \
                if (bin >= tX){ \
                    int pos = atomicAdd(&gcnt[bc0+cls], 1); \
                    if (pos < CAP){ \
                        gsc[(size_t)(bc0+cls)*CAP + pos] = sc; \
                        gix[(size_t)(bc0+cls)*CAP + pos] = g.nb + 3*(g.p+J); } } } }
            DOJ(0,p0,c4.x) DOJ(1,p1,c4.y) DOJ(2,p2,c4.z) DOJ(3,p3,c4.w)
#undef DOJ
            pr += g.P;
        }
    }
}

// ---------------- per-(b,c): sort candidates + NMS + write out --------------
__global__ __launch_bounds__(256)
void sortnms_kernel(const float* __restrict__ gsc, const int* __restrict__ gix,
                    const int* __restrict__ gcnt, const float* __restrict__ boxes,
                    float* __restrict__ out)
{
    int c = blockIdx.x, b = blockIdx.y, tid = threadIdx.x;
    int bc = b*NCLS + c;
    __shared__ float cs[CAP];
    __shared__ int   ci[CAP];
    int n = gcnt[bc]; if (n > CAP) n = CAP;
    for (int t=tid; t<CAP; t+=256){
        if (t < n){ cs[t] = gsc[(size_t)bc*CAP + t]; ci[t] = gix[(size_t)bc*CAP + t]; }
        else { cs[t] = -INFINITY; ci[t] = 0x7FFFFFFF; }
    }
    __syncthreads();
    int S = 128; while (S < n) S <<= 1;
    for (int k=2; k<=S; k<<=1){
        for (int j=k>>1; j>0; j>>=1){
            for (int t=tid; t<S; t+=256){
                int ixj = t ^ j;
                if (ixj > t){
                    float s1 = cs[t], s2 = cs[ixj];
                    int   i1 = ci[t], i2 = ci[ixj];
                    bool b2_first = (s2 > s1) || (s2 == s1 && i2 < i1);
                    bool b1_first = (s1 > s2) || (s1 == s2 && i1 < i2);
                    bool desc = ((t & k) == 0);
                    bool sw = desc ? b2_first : b1_first;
                    if (sw){ cs[t]=s2; cs[ixj]=s1; ci[t]=i2; ci[ixj]=i1; }
                }
            }
            __syncthreads();
        }
    }

    // NMS on wave 0 (shfl broadcast, no barriers)
    int w = tid >> 6, lane = tid & 63;
    if (w == 0){
        int o0 = bc*TOPK;
        int nn = n < TOPK ? n : TOPK;
        float ay1=0.f,ax1=0.f,ay2=0.f,ax2=0.f,aar=0.f,asc=0.f; int ak=0;
        float by1=0.f,bx1=0.f,by2=0.f,bx2=0.f,bar_=0.f,bsc=0.f; int bk=0;
        {
            float s = cs[lane];
            if (s > 0.3f){
                asc = s;
                size_t q = ((size_t)b*NBOX + ci[lane])*4;
                ay1=boxes[q]; ax1=boxes[q+1]; ay2=boxes[q+2]; ax2=boxes[q+3]; ak=1;
            }
            aar = (ay2-ay1)*(ax2-ax1);
        }
        if (lane + 64 < TOPK){
            float s = cs[lane+64];
            if (s > 0.3f){
                bsc = s;
                size_t q = ((size_t)b*NBOX + ci[lane+64])*4;
                by1=boxes[q]; bx1=boxes[q+1]; by2=boxes[q+2]; bx2=boxes[q+3]; bk=1;
            }
            bar_ = (by2-by1)*(bx2-bx1);
        }
        for (int i=0; i<nn; i++){
            float iy1,ix1,iy2,ix2,iar; int ik;
            if (i < 64){
                iy1=__shfl(ay1,i); ix1=__shfl(ax1,i); iy2=__shfl(ay2,i); ix2=__shfl(ax2,i);
                iar=__shfl(aar,i); ik=__shfl(ak,i);
            } else {
                int l = i - 64;
                iy1=__shfl(by1,l); ix1=__shfl(bx1,l); iy2=__shfl(by2,l); ix2=__shfl(bx2,l);
                iar=__shfl(bar_,l); ik=__shfl(bk,l);
            }
            if (ik){
                if (ak && lane > i){
                    float q1=fmaxf(iy1,ay1), q2=fmaxf(ix1,ax1);
                    float q3=fminf(iy2,ay2), q4=fminf(ix2,ax2);
                    float inter = fmaxf(q3-q1,0.0f)*fmaxf(q4-q2,0.0f);
                    float iou = inter/(iar + aar - inter + 1e-9f);
                    if (iou > 0.3f) ak = 0;
                }
                if (bk && lane + 64 > i){
                    float q1=fmaxf(iy1,by1), q2=fmaxf(ix1,bx1);
                    float q3=fminf(iy2,by2), q4=fminf(ix2,bx2);
                    float inter = fmaxf(q3-q1,0.0f)*fmaxf(q4-q2,0.0f);
                    float iou = inter/(iar + bar_ - inter + 1e-9f);
                    if (iou > 0.3f) bk = 0;
                }
            }
        }
        {
            float k = ak ? 1.0f : 0.0f;
            size_t o5 = ((size_t)(o0+lane))*5;
            out[o5+0]=ay1*k; out[o5+1]=ax1*k; out[o5+2]=ay2*k; out[o5+3]=ax2*k; out[o5+4]=asc*k;
        }
        if (lane + 64 < TOPK){
            float k = bk ? 1.0f : 0.0f;
            size_t o5 = ((size_t)(o0+lane+64))*5;
            out[o5+0]=by1*k; out[o5+1]=bx1*k; out[o5+2]=by2*k; out[o5+3]=bx2*k; out[o5+4]=bsc*k;
        }
    }
}

// -------- per-image top-50 cap via histogram select (no serial argmax) ------
__global__ __launch_bounds__(1024)
void cap_kernel(float* __restrict__ out)
{
    int b = blockIdx.x, tid = threadIdx.x;
    __shared__ unsigned int h[256];
    __shared__ int sufA[256], sufB[256];
    __shared__ float cs[512];
    __shared__ int   ci[512];
    __shared__ int cnt, T50;
    __shared__ unsigned char msk[NSLOT];
    if (tid < 256) h[tid] = 0;
    if (tid == 0){ cnt = 0; T50 = 0; }
    for (int u=tid; u<NSLOT; u+=1024) msk[u] = 0;
    __syncthreads();

    // histogram of positive scores (kept scores are all > 0.3)
    for (int u=tid; u<NSLOT; u+=1024){
        float v = out[((size_t)b*NSLOT + u)*5 + 4];
        if (v > 0.0f) atomicAdd(&h[BIN_OF(v)], 1u);
    }
    __syncthreads();

    // suffix scan (first 256 threads)
    if (tid < 256) sufA[tid] = (int)h[tid];
    __syncthreads();
    int* cur = sufA; int* nxt = sufB;
    for (int d=1; d<256; d<<=1){
        if (tid < 256) nxt[tid] = cur[tid] + ((tid+d) < 256 ? cur[tid+d] : 0);
        __syncthreads();
        int* t_ = cur; cur = nxt; nxt = t_;
    }
    if (tid < 256){
        if (cur[tid] >= 50 && (tid == 255 || cur[tid+1] < 50)) T50 = tid;
    }
    __syncthreads();
    int T = T50;

    // compact candidates (bin >= T50), ~50-100 expected
    for (int u=tid; u<NSLOT; u+=1024){
        float v = out[((size_t)b*NSLOT + u)*5 + 4];
        if (v > 0.0f && BIN_OF(v) >= T){
            int pos = atomicAdd(&cnt, 1);
            if (pos < 512){ cs[pos] = v; ci[pos] = u; }
        }
    }
    __syncthreads();
    int n = cnt; if (n > 512) n = 512;
    for (int t=tid; t<512; t+=1024){
        if (t >= n){ cs[t] = -INFINITY; ci[t] = 0x7FFFFFFF; }
    }
    __syncthreads();

    // bitonic sort (v desc, idx asc)
    int S = 64; while (S < n) S <<= 1;
    for (int k=2; k<=S; k<<=1){
        for (int j=k>>1; j>0; j>>=1){
            for (int t=tid; t<S; t+=1024){
                int ixj = t ^ j;
                if (ixj > t){
                    float s1 = cs[t], s2 = cs[ixj];
                    int   i1 = ci[t], i2 = ci[ixj];
                    bool b2_first = (s2 > s1) || (s2 == s1 && i2 < i1);
                    bool b1_first = (s1 > s2) || (s1 == s2 && i1 < i2);
                    bool desc = ((t & k) == 0);
                    bool sw = desc ? b2_first : b1_first;
                    if (sw){ cs[t]=s2; cs[ixj]=s1; ci[t]=i2; ci[ixj]=i1; }
                }
            }
            __syncthreads();
        }
    }

    // mark top min(50, n)
    if (tid < 50 && tid < n) msk[ci[tid]] = 1;
    __syncthreads();

    // zero all positive rows not selected
    for (int u=tid; u<NSLOT; u+=1024){
        size_t o5 = ((size_t)b*NSLOT + u)*5;
        float v = out[o5 + 4];
        if (v > 0.0f && !msk[u]){
            out[o5+0]=0.f; out[o5+1]=0.f; out[o5+2]=0.f; out[o5+3]=0.f; out[o5+4]=0.f;
        }
    }
}

extern "C" void kernel_launch(void* const* d_in, const int* in_sizes, int n_in,
                              void* d_out, int out_size, void* d_ws, size_t ws_size,
                              hipStream_t stream)
{
    const float* f0 = (const float*)d_in[0];
    const float* f1 = (const float*)d_in[1];
    const float* f2 = (const float*)d_in[2];
    const float* anchors = (const float*)d_in[3];
    const float* ishape  = (const float*)d_in[4];
    float* out = (float*)d_out;

    float* boxes = (float*)d_ws;                                   // 16*22743*4
    float* conf2 = boxes + (size_t)BATCH*NBOX*4;                   // 16*22752
    unsigned int* ghist = (unsigned int*)(conf2 + (size_t)BATCH*TPAD); // 1280*256
    int* gcnt = (int*)(ghist + (size_t)BATCH*NCLS*256);            // 1280 (contiguous after ghist)
    int* tb   = gcnt + BATCH*NCLS;                                 // 1280
    float* gsc = (float*)(tb + BATCH*NCLS);                        // 1280*1024
    int*   gix = (int*)(gsc + (size_t)BATCH*NCLS*CAP);             // 1280*1024

    dim3 dgrid((TPAD + 255)/256, BATCH);
    decode_kernel<<<dgrid, 256, 0, stream>>>(f0, f1, f2, anchors, ishape,
                                             boxes, conf2, ghist);

    dim3 hgrid(NCLS/4, BATCH, NCH);
    hist_kernel<<<hgrid, 256, 0, stream>>>(f0, f1, f2, conf2, ghist);

    tb_kernel<<<BATCH*NCLS, 256, 0, stream>>>(ghist, tb);

    compact_kernel<<<hgrid, 256, 0, stream>>>(f0, f1, f2, conf2, tb, gcnt, gsc, gix);

    dim3 sgrid(NCLS, BATCH);
    sortnms_kernel<<<sgrid, 256, 0, stream>>>(gsc, gix, gcnt, boxes, out);

    cap_kernel<<<BATCH, 1024, 0, stream>>>(out);
}

// Round 6
// 143.482 us; speedup vs baseline: 1.8545x; 1.0315x over previous
//
#include <hip/hip_runtime.h>
#include <math.h>

#define BATCH 16
#define NCLS 80
#define TOPK 100
#define NBOX 22743
#define NSLOT (NCLS*TOPK)   // 8000 per image
#define TPAD 22752          // padded (s,a)-major total per image
#define CAP 1024
#define NSEG 18
#define NZERO (BATCH*NCLS*256 + BATCH*NCLS)   // ghist + gcnt words

__device__ __forceinline__ float sigf(float x){ return 1.0f/(1.0f + expf(-x)); }

#define BIN_OF(sc) ({ int _b = (int)(__float_as_uint(sc)>>16) - 0x3E99; _b < 0 ? 0 : (_b > 255 ? 255 : _b); })

// segment: one (scale,anchor[,chunk]) row slice; all fields block-uniform
struct Seg { const float* fbase; int a; int P; int qc; int confb; int nb; int lqoff; int tailq; };
__device__ __forceinline__ Seg segdec(int z, const float* f0, const float* f1, const float* f2){
    Seg s;
    if (z < 3){       s.a=z;   s.P=361;  s.qc=91;  s.confb=z*364;                s.nb=z;        s.fbase=f0; s.lqoff=0;      s.tailq=90; }
    else if (z < 6){  int a=z-3; s.a=a;  s.P=1444; s.qc=361; s.confb=1092+a*1444; s.nb=1083+a;  s.fbase=f1; s.lqoff=0;      s.tailq=-1; }
    else { int t=z-6; int a=t>>2, ch=t&3; s.a=a; s.P=5776; s.qc=361;
           s.confb=5424+a*5776+ch*1444;  s.nb=5415+a;  s.fbase=f2; s.lqoff=ch*361; s.tailq=-1; }
    return s;
}

// ------- decode: boxes + conf (padded (s,a)-major); also zeroes ghist+gcnt ----
__global__ __launch_bounds__(256)
void decode_kernel(const float* __restrict__ f0, const float* __restrict__ f1,
                   const float* __restrict__ f2, const float* __restrict__ anchors,
                   const float* __restrict__ ishape,
                   float* __restrict__ boxes, float* __restrict__ conf2,
                   unsigned int* __restrict__ gzero)
{
    int tid = threadIdx.x;
    int b = blockIdx.y;
    int r = blockIdx.x*blockDim.x + tid;
    int gid = (b*gridDim.x + blockIdx.x)*256 + tid;
    if (gid < NZERO) gzero[gid] = 0u;
    if (r >= TPAD) return;
    int sa, p;
    if (r < 1092){ sa = r/364; p = r - sa*364; }
    else if (r < 5424){ int q = r-1092; sa = 3 + q/1444; p = q - (sa-3)*1444; }
    else { int q = r-5424; sa = 6 + q/5776; p = q - (sa-6)*5776; }
    int s = (sa>=6)?2:((sa>=3)?1:0);
    int a = sa - 3*s;
    const float* f; int P, G, off, abase;
    if (s==0){ f=f0; P=361;  G=19; off=0;    abase=6; }
    else if (s==1){ f=f1; P=1444; G=38; off=1083; abase=3; }
    else        { f=f2; P=5776; G=76; off=5415; abase=0; }
    size_t cidx = (size_t)b*TPAD + r;
    if (p >= P){ conf2[cidx] = 0.0f; return; }

    const float* fb = f + ((size_t)b*255 + a*85)*(size_t)P;
    float tx = fb[(size_t)0*P + p];
    float ty = fb[(size_t)1*P + p];
    float tw = fb[(size_t)2*P + p];
    float th = fb[(size_t)3*P + p];
    float tc = fb[(size_t)4*P + p];
    int yy = p / G, xx = p - yy*G;
    float g = (float)G;
    float aw = anchors[(abase+a)*2+0];
    float ah = anchors[(abase+a)*2+1];
    float xn = (sigf(tx) + (float)xx) / g;
    float yn = (sigf(ty) + (float)yy) / g;
    float wn = aw * expf(tw) / 608.0f;
    float hn = ah * expf(th) / 608.0f;
    float ih = ishape[0], iw = ishape[1];
    float m  = fminf(608.0f/ih, 608.0f/iw);
    float nh = rintf(ih*m), nw = rintf(iw*m);
    float offy = (608.0f - nh) / 2.0f / 608.0f;
    float offx = (608.0f - nw) / 2.0f / 608.0f;
    float scy = 608.0f/nh, scx = 608.0f/nw;
    float y = (yn - offy)*scy;
    float x = (xn - offx)*scx;
    float hh = hn*scy, ww = wn*scx;
    int n = off + p*3 + a;
    size_t o = ((size_t)b*NBOX + n)*4;
    boxes[o+0] = (y - hh/2.0f)*ih;
    boxes[o+1] = (x - ww/2.0f)*iw;
    boxes[o+2] = (y + hh/2.0f)*ih;
    boxes[o+3] = (x + ww/2.0f)*iw;

    conf2[cidx] = sigf(tc);
}

// ---------------- histogram pass: 4 classes/block, one segment/block --------
__global__ __launch_bounds__(256)
void hist_kernel(const float* __restrict__ f0, const float* __restrict__ f1,
                 const float* __restrict__ f2, const float* __restrict__ conf2,
                 unsigned int* __restrict__ ghist)
{
    int cg = blockIdx.x, b = blockIdx.y, z = blockIdx.z, tid = threadIdx.x;
    int c0 = cg*4;
    __shared__ unsigned int h[4][256];
    h[0][tid]=0; h[1][tid]=0; h[2][tid]=0; h[3][tid]=0;
    __syncthreads();
    Seg sg = segdec(z, f0, f1, f2);
    const int P = sg.P, qc = sg.qc;
    const float* cfp = conf2 + (size_t)b*TPAD + sg.confb;
    const float* prb = sg.fbase + ((size_t)b*255 + sg.a*85 + 5 + c0)*(size_t)P + sg.lqoff*4;

    int lqA = tid, lqB = tid + 256;
    bool vA = lqA < qc, vB = lqB < qc;
    float4 cfA, cfB, A0, A1, A2, A3, B0, B1, B2, B3;
    if (vA){
        const float* pA = prb + lqA*4;
        cfA = *(const float4*)(cfp + lqA*4);
        A0 = *(const float4*)pA;       A1 = *(const float4*)(pA + P);
        A2 = *(const float4*)(pA + 2*P); A3 = *(const float4*)(pA + 3*P);
    }
    if (vB){
        const float* pB = prb + lqB*4;
        cfB = *(const float4*)(cfp + lqB*4);
        B0 = *(const float4*)pB;       B1 = *(const float4*)(pB + P);
        B2 = *(const float4*)(pB + 2*P); B3 = *(const float4*)(pB + 3*P);
    }
#define HQUAD(cls, Q, CF) { \
    float s0 = CF.x*sigf(Q.x), s1 = CF.y*sigf(Q.y), s2 = CF.z*sigf(Q.z), s3 = CF.w*sigf(Q.w); \
    if (s0 > 0.3f) atomicAdd(&h[cls][BIN_OF(s0)], 1u); \
    if (s1 > 0.3f) atomicAdd(&h[cls][BIN_OF(s1)], 1u); \
    if (s2 > 0.3f) atomicAdd(&h[cls][BIN_OF(s2)], 1u); \
    if (s3 > 0.3f) atomicAdd(&h[cls][BIN_OF(s3)], 1u); }
    if (vA){
        if (lqA == sg.tailq){
            A0.y=A0.z=A0.w=-INFINITY; A1.y=A1.z=A1.w=-INFINITY;
            A2.y=A2.z=A2.w=-INFINITY; A3.y=A3.z=A3.w=-INFINITY;
        }
        HQUAD(0, A0, cfA) HQUAD(1, A1, cfA) HQUAD(2, A2, cfA) HQUAD(3, A3, cfA)
    }
    if (vB){
        HQUAD(0, B0, cfB) HQUAD(1, B1, cfB) HQUAD(2, B2, cfB) HQUAD(3, B3, cfB)
    }
#undef HQUAD
    __syncthreads();
    size_t hb = ((size_t)b*NCLS + c0)*256 + tid;
    if (h[0][tid]) atomicAdd(&ghist[hb      ], h[0][tid]);
    if (h[1][tid]) atomicAdd(&ghist[hb + 256], h[1][tid]);
    if (h[2][tid]) atomicAdd(&ghist[hb + 512], h[2][tid]);
    if (h[3][tid]) atomicAdd(&ghist[hb + 768], h[3][tid]);
}

// ---------------- threshold-bin per (b,c) ----------------
__global__ __launch_bounds__(256)
void tb_kernel(const unsigned int* __restrict__ ghist, int* __restrict__ tb)
{
    int bc = blockIdx.x, tid = threadIdx.x;
    __shared__ int sufA[256], sufB[256];
    __shared__ int TbS;
    if (tid == 0) TbS = 0;
    sufA[tid] = (int)ghist[(size_t)bc*256 + tid];
    __syncthreads();
    int* cur = sufA; int* nxt = sufB;
    for (int d=1; d<256; d<<=1){
        int v = cur[tid] + ((tid+d) < 256 ? cur[tid+d] : 0);
        nxt[tid] = v;
        __syncthreads();
        int* t_ = cur; cur = nxt; nxt = t_;
    }
    if (cur[tid] >= TOPK && (tid == 255 || cur[tid+1] < TOPK)) TbS = tid;
    __syncthreads();
    if (tid == 0) tb[bc] = TbS;
}

// ---------------- compact pass: candidates (bin >= Tb) to global ------------
__global__ __launch_bounds__(256)
void compact_kernel(const float* __restrict__ f0, const float* __restrict__ f1,
                    const float* __restrict__ f2, const float* __restrict__ conf2,
                    const int* __restrict__ tb, int* __restrict__ gcnt,
                    float* __restrict__ gsc, int* __restrict__ gix)
{
    int cg = blockIdx.x, b = blockIdx.y, z = blockIdx.z, tid = threadIdx.x;
    int c0 = cg*4;
    int bc0 = b*NCLS + c0;
    int t0 = tb[bc0], t1 = tb[bc0+1], t2 = tb[bc0+2], t3 = tb[bc0+3];
    Seg sg = segdec(z, f0, f1, f2);
    const int P = sg.P, qc = sg.qc;
    const float* cfp = conf2 + (size_t)b*TPAD + sg.confb;
    const float* prb = sg.fbase + ((size_t)b*255 + sg.a*85 + 5 + c0)*(size_t)P + sg.lqoff*4;

    int lqA = tid, lqB = tid + 256;
    bool vA = lqA < qc, vB = lqB < qc;
    float4 cfA, cfB, A0, A1, A2, A3, B0, B1, B2, B3;
    if (vA){
        const float* pA = prb + lqA*4;
        cfA = *(const float4*)(cfp + lqA*4);
        A0 = *(const float4*)pA;       A1 = *(const float4*)(pA + P);
        A2 = *(const float4*)(pA + 2*P); A3 = *(const float4*)(pA + 3*P);
    }
    if (vB){
        const float* pB = prb + lqB*4;
        cfB = *(const float4*)(cfp + lqB*4);
        B0 = *(const float4*)pB;       B1 = *(const float4*)(pB + P);
        B2 = *(const float4*)(pB + 2*P); B3 = *(const float4*)(pB + 3*P);
    }
#define DOJ(cls, TX, SC, IDX) { \
    if ((SC) > 0.3f){ int bin = BIN_OF(SC); \
        if (bin >= (TX)){ \
            int pos = atomicAdd(&gcnt[bc0+cls], 1); \
            if (pos < CAP){ \
                gsc[(size_t)(bc0+cls)*CAP + pos] = (SC); \
                gix[(size_t)(bc0+cls)*CAP + pos] = (IDX); } } } }
#define CQUAD(cls, Q, CF, TX, PBASE) { \
    float s0 = CF.x*sigf(Q.x), s1 = CF.y*sigf(Q.y), s2 = CF.z*sigf(Q.z), s3 = CF.w*sigf(Q.w); \
    DOJ(cls, TX, s0, sg.nb + 3*((PBASE)+0)) \
    DOJ(cls, TX, s1, sg.nb + 3*((PBASE)+1)) \
    DOJ(cls, TX, s2, sg.nb + 3*((PBASE)+2)) \
    DOJ(cls, TX, s3, sg.nb + 3*((PBASE)+3)) }
    if (vA){
        if (lqA == sg.tailq){
            A0.y=A0.z=A0.w=-INFINITY; A1.y=A1.z=A1.w=-INFINITY;
            A2.y=A2.z=A2.w=-INFINITY; A3.y=A3.z=A3.w=-INFINITY;
        }
        int pbase = (sg.lqoff + lqA)*4;
        CQUAD(0, A0, cfA, t0, pbase) CQUAD(1, A1, cfA, t1, pbase)
        CQUAD(2, A2, cfA, t2, pbase) CQUAD(3, A3, cfA, t3, pbase)
    }
    if (vB){
        int pbase = (sg.lqoff + lqB)*4;
        CQUAD(0, B0, cfB, t0, pbase) CQUAD(1, B1, cfB, t1, pbase)
        CQUAD(2, B2, cfB, t2, pbase) CQUAD(3, B3, cfB, t3, pbase)
    }
#undef CQUAD
#undef DOJ
}

// ---------------- per-(b,c): sort candidates + NMS + write out --------------
__global__ __launch_bounds__(256)
void sortnms_kernel(const float* __restrict__ gsc, const int* __restrict__ gix,
                    const int* __restrict__ gcnt, const float* __restrict__ boxes,
                    float* __restrict__ out)
{
    int c = blockIdx.x, b = blockIdx.y, tid = threadIdx.x;
    int bc = b*NCLS + c;
    __shared__ float cs[CAP];
    __shared__ int   ci[CAP];
    int n = gcnt[bc]; if (n > CAP) n = CAP;
    for (int t=tid; t<CAP; t+=256){
        if (t < n){ cs[t] = gsc[(size_t)bc*CAP + t]; ci[t] = gix[(size_t)bc*CAP + t]; }
        else { cs[t] = -INFINITY; ci[t] = 0x7FFFFFFF; }
    }
    __syncthreads();
    int S = 128; while (S < n) S <<= 1;
    for (int k=2; k<=S; k<<=1){
        for (int j=k>>1; j>0; j>>=1){
            for (int t=tid; t<S; t+=256){
                int ixj = t ^ j;
                if (ixj > t){
                    float s1 = cs[t], s2 = cs[ixj];
                    int   i1 = ci[t], i2 = ci[ixj];
                    bool b2_first = (s2 > s1) || (s2 == s1 && i2 < i1);
                    bool b1_first = (s1 > s2) || (s1 == s2 && i1 < i2);
                    bool desc = ((t & k) == 0);
                    bool sw = desc ? b2_first : b1_first;
                    if (sw){ cs[t]=s2; cs[ixj]=s1; ci[t]=i2; ci[ixj]=i1; }
                }
            }
            __syncthreads();
        }
    }

    // NMS on wave 0 (shfl broadcast, no barriers)
    int w = tid >> 6, lane = tid & 63;
    if (w == 0){
        int o0 = bc*TOPK;
        int nn = n < TOPK ? n : TOPK;
        float ay1=0.f,ax1=0.f,ay2=0.f,ax2=0.f,aar=0.f,asc=0.f; int ak=0;
        float by1=0.f,bx1=0.f,by2=0.f,bx2=0.f,bar_=0.f,bsc=0.f; int bk=0;
        {
            float s = cs[lane];
            if (s > 0.3f){
                asc = s;
                size_t q = ((size_t)b*NBOX + ci[lane])*4;
                ay1=boxes[q]; ax1=boxes[q+1]; ay2=boxes[q+2]; ax2=boxes[q+3]; ak=1;
            }
            aar = (ay2-ay1)*(ax2-ax1);
        }
        if (lane + 64 < TOPK){
            float s = cs[lane+64];
            if (s > 0.3f){
                bsc = s;
                size_t q = ((size_t)b*NBOX + ci[lane+64])*4;
                by1=boxes[q]; bx1=boxes[q+1]; by2=boxes[q+2]; bx2=boxes[q+3]; bk=1;
            }
            bar_ = (by2-by1)*(bx2-bx1);
        }
        for (int i=0; i<nn; i++){
            float iy1,ix1,iy2,ix2,iar; int ik;
            if (i < 64){
                iy1=__shfl(ay1,i); ix1=__shfl(ax1,i); iy2=__shfl(ay2,i); ix2=__shfl(ax2,i);
                iar=__shfl(aar,i); ik=__shfl(ak,i);
            } else {
                int l = i - 64;
                iy1=__shfl(by1,l); ix1=__shfl(bx1,l); iy2=__shfl(by2,l); ix2=__shfl(bx2,l);
                iar=__shfl(bar_,l); ik=__shfl(bk,l);
            }
            if (ik){
                if (ak && lane > i){
                    float q1=fmaxf(iy1,ay1), q2=fmaxf(ix1,ax1);
                    float q3=fminf(iy2,ay2), q4=fminf(ix2,ax2);
                    float inter = fmaxf(q3-q1,0.0f)*fmaxf(q4-q2,0.0f);
                    float iou = inter/(iar + aar - inter + 1e-9f);
                    if (iou > 0.3f) ak = 0;
                }
                if (bk && lane + 64 > i){
                    float q1=fmaxf(iy1,by1), q2=fmaxf(ix1,bx1);
                    float q3=fminf(iy2,by2), q4=fminf(ix2,bx2);
                    float inter = fmaxf(q3-q1,0.0f)*fmaxf(q4-q2,0.0f);
                    float iou = inter/(iar + bar_ - inter + 1e-9f);
                    if (iou > 0.3f) bk = 0;
                }
            }
        }
        {
            float k = ak ? 1.0f : 0.0f;
            size_t o5 = ((size_t)(o0+lane))*5;
            out[o5+0]=ay1*k; out[o5+1]=ax1*k; out[o5+2]=ay2*k; out[o5+3]=ax2*k; out[o5+4]=asc*k;
        }
        if (lane + 64 < TOPK){
            float k = bk ? 1.0f : 0.0f;
            size_t o5 = ((size_t)(o0+lane+64))*5;
            out[o5+0]=by1*k; out[o5+1]=bx1*k; out[o5+2]=by2*k; out[o5+3]=bx2*k; out[o5+4]=bsc*k;
        }
    }
}

// -------- per-image top-50 cap via histogram select (no serial argmax) ------
__global__ __launch_bounds__(1024)
void cap_kernel(float* __restrict__ out)
{
    int b = blockIdx.x, tid = threadIdx.x;
    __shared__ unsigned int h[256];
    __shared__ int sufA[256], sufB[256];
    __shared__ float cs[512];
    __shared__ int   ci[512];
    __shared__ int cnt, T50;
    __shared__ unsigned char msk[NSLOT];
    if (tid < 256) h[tid] = 0;
    if (tid == 0){ cnt = 0; T50 = 0; }
    for (int u=tid; u<NSLOT; u+=1024) msk[u] = 0;
    __syncthreads();

    for (int u=tid; u<NSLOT; u+=1024){
        float v = out[((size_t)b*NSLOT + u)*5 + 4];
        if (v > 0.0f) atomicAdd(&h[BIN_OF(v)], 1u);
    }
    __syncthreads();

    if (tid < 256) sufA[tid] = (int)h[tid];
    __syncthreads();
    int* cur = sufA; int* nxt = sufB;
    for (int d=1; d<256; d<<=1){
        if (tid < 256) nxt[tid] = cur[tid] + ((tid+d) < 256 ? cur[tid+d] : 0);
        __syncthreads();
        int* t_ = cur; cur = nxt; nxt = t_;
    }
    if (tid < 256){
        if (cur[tid] >= 50 && (tid == 255 || cur[tid+1] < 50)) T50 = tid;
    }
    __syncthreads();
    int T = T50;

    for (int u=tid; u<NSLOT; u+=1024){
        float v = out[((size_t)b*NSLOT + u)*5 + 4];
        if (v > 0.0f && BIN_OF(v) >= T){
            int pos = atomicAdd(&cnt, 1);
            if (pos < 512){ cs[pos] = v; ci[pos] = u; }
        }
    }
    __syncthreads();
    int n = cnt; if (n > 512) n = 512;
    for (int t=tid; t<512; t+=1024){
        if (t >= n){ cs[t] = -INFINITY; ci[t] = 0x7FFFFFFF; }
    }
    __syncthreads();

    int S = 64; while (S < n) S <<= 1;
    for (int k=2; k<=S; k<<=1){
        for (int j=k>>1; j>0; j>>=1){
            for (int t=tid; t<S; t+=1024){
                int ixj = t ^ j;
                if (ixj > t){
                    float s1 = cs[t], s2 = cs[ixj];
                    int   i1 = ci[t], i2 = ci[ixj];
                    bool b2_first = (s2 > s1) || (s2 == s1 && i2 < i1);
                    bool b1_first = (s1 > s2) || (s1 == s2 && i1 < i2);
                    bool desc = ((t & k) == 0);
                    bool sw = desc ? b2_first : b1_first;
                    if (sw){ cs[t]=s2; cs[ixj]=s1; ci[t]=i2; ci[ixj]=i1; }
                }
            }
            __syncthreads();
        }
    }

    if (tid < 50 && tid < n) msk[ci[tid]] = 1;
    __syncthreads();

    for (int u=tid; u<NSLOT; u+=1024){
        size_t o5 = ((size_t)b*NSLOT + u)*5;
        float v = out[o5 + 4];
        if (v > 0.0f && !msk[u]){
            out[o5+0]=0.f; out[o5+1]=0.f; out[o5+2]=0.f; out[o5+3]=0.f; out[o5+4]=0.f;
        }
    }
}

extern "C" void kernel_launch(void* const* d_in, const int* in_sizes, int n_in,
                              void* d_out, int out_size, void* d_ws, size_t ws_size,
                              hipStream_t stream)
{
    const float* f0 = (const float*)d_in[0];
    const float* f1 = (const float*)d_in[1];
    const float* f2 = (const float*)d_in[2];
    const float* anchors = (const float*)d_in[3];
    const float* ishape  = (const float*)d_in[4];
    float* out = (float*)d_out;

    float* boxes = (float*)d_ws;                                   // 16*22743*4
    float* conf2 = boxes + (size_t)BATCH*NBOX*4;                   // 16*22752
    unsigned int* ghist = (unsigned int*)(conf2 + (size_t)BATCH*TPAD); // 1280*256
    int* gcnt = (int*)(ghist + (size_t)BATCH*NCLS*256);            // 1280 (contiguous after ghist)
    int* tb   = gcnt + BATCH*NCLS;                                 // 1280
    float* gsc = (float*)(tb + BATCH*NCLS);                        // 1280*1024
    int*   gix = (int*)(gsc + (size_t)BATCH*NCLS*CAP);             // 1280*1024

    dim3 dgrid((TPAD + 255)/256, BATCH);
    decode_kernel<<<dgrid, 256, 0, stream>>>(f0, f1, f2, anchors, ishape,
                                             boxes, conf2, ghist);

    dim3 hgrid(NCLS/4, BATCH, NSEG);
    hist_kernel<<<hgrid, 256, 0, stream>>>(f0, f1, f2, conf2, ghist);

    tb_kernel<<<BATCH*NCLS, 256, 0, stream>>>(ghist, tb);

    compact_kernel<<<hgrid, 256, 0, stream>>>(f0, f1, f2, conf2, tb, gcnt, gsc, gix);

    dim3 sgrid(NCLS, BATCH);
    sortnms_kernel<<<sgrid, 256, 0, stream>>>(gsc, gix, gcnt, boxes, out);

    cap_kernel<<<BATCH, 1024, 0, stream>>>(out);
}

// Round 7
// 142.715 us; speedup vs baseline: 1.8644x; 1.0054x over previous
//
#include <hip/hip_runtime.h>
#include <math.h>

#define BATCH 16
#define NCLS 80
#define TOPK 100
#define NBOX 22743
#define NSLOT (NCLS*TOPK)   // 8000 per image
#define TPAD 22752          // padded (s,a)-major total per image
#define CAP 1024
#define NSEG 18
#define NZERO (BATCH*NCLS*256 + BATCH*NCLS)   // ghist + gcnt words

__device__ __forceinline__ float sigf(float x){ return 1.0f/(1.0f + expf(-x)); }

#define BIN_OF(sc) ({ int _b = (int)(__float_as_uint(sc)>>16) - 0x3E99; _b < 0 ? 0 : (_b > 255 ? 255 : _b); })

// segment: one (scale,anchor[,chunk]) row slice; all fields block-uniform
struct Seg { const float* fbase; int a; int P; int qc; int confb; int nb; int lqoff; int tailq; };
__device__ __forceinline__ Seg segdec(int z, const float* f0, const float* f1, const float* f2){
    Seg s;
    if (z < 3){       s.a=z;   s.P=361;  s.qc=91;  s.confb=z*364;                s.nb=z;        s.fbase=f0; s.lqoff=0;      s.tailq=90; }
    else if (z < 6){  int a=z-3; s.a=a;  s.P=1444; s.qc=361; s.confb=1092+a*1444; s.nb=1083+a;  s.fbase=f1; s.lqoff=0;      s.tailq=-1; }
    else { int t=z-6; int a=t>>2, ch=t&3; s.a=a; s.P=5776; s.qc=361;
           s.confb=5424+a*5776+ch*1444;  s.nb=5415+a;  s.fbase=f2; s.lqoff=ch*361; s.tailq=-1; }
    return s;
}

// ------- decode: boxes + conf (padded (s,a)-major); also zeroes ghist+gcnt ----
__global__ __launch_bounds__(256)
void decode_kernel(const float* __restrict__ f0, const float* __restrict__ f1,
                   const float* __restrict__ f2, const float* __restrict__ anchors,
                   const float* __restrict__ ishape,
                   float* __restrict__ boxes, float* __restrict__ conf2,
                   unsigned int* __restrict__ gzero)
{
    int tid = threadIdx.x;
    int b = blockIdx.y;
    int r = blockIdx.x*blockDim.x + tid;
    int gid = (b*gridDim.x + blockIdx.x)*256 + tid;
    if (gid < NZERO) gzero[gid] = 0u;
    if (r >= TPAD) return;
    int sa, p;
    if (r < 1092){ sa = r/364; p = r - sa*364; }
    else if (r < 5424){ int q = r-1092; sa = 3 + q/1444; p = q - (sa-3)*1444; }
    else { int q = r-5424; sa = 6 + q/5776; p = q - (sa-6)*5776; }
    int s = (sa>=6)?2:((sa>=3)?1:0);
    int a = sa - 3*s;
    const float* f; int P, G, off, abase;
    if (s==0){ f=f0; P=361;  G=19; off=0;    abase=6; }
    else if (s==1){ f=f1; P=1444; G=38; off=1083; abase=3; }
    else        { f=f2; P=5776; G=76; off=5415; abase=0; }
    size_t cidx = (size_t)b*TPAD + r;
    if (p >= P){ conf2[cidx] = 0.0f; return; }

    const float* fb = f + ((size_t)b*255 + a*85)*(size_t)P;
    float tx = fb[(size_t)0*P + p];
    float ty = fb[(size_t)1*P + p];
    float tw = fb[(size_t)2*P + p];
    float th = fb[(size_t)3*P + p];
    float tc = fb[(size_t)4*P + p];
    int yy = p / G, xx = p - yy*G;
    float g = (float)G;
    float aw = anchors[(abase+a)*2+0];
    float ah = anchors[(abase+a)*2+1];
    float xn = (sigf(tx) + (float)xx) / g;
    float yn = (sigf(ty) + (float)yy) / g;
    float wn = aw * expf(tw) / 608.0f;
    float hn = ah * expf(th) / 608.0f;
    float ih = ishape[0], iw = ishape[1];
    float m  = fminf(608.0f/ih, 608.0f/iw);
    float nh = rintf(ih*m), nw = rintf(iw*m);
    float offy = (608.0f - nh) / 2.0f / 608.0f;
    float offx = (608.0f - nw) / 2.0f / 608.0f;
    float scy = 608.0f/nh, scx = 608.0f/nw;
    float y = (yn - offy)*scy;
    float x = (xn - offx)*scx;
    float hh = hn*scy, ww = wn*scx;
    int n = off + p*3 + a;
    size_t o = ((size_t)b*NBOX + n)*4;
    boxes[o+0] = (y - hh/2.0f)*ih;
    boxes[o+1] = (x - ww/2.0f)*iw;
    boxes[o+2] = (y + hh/2.0f)*ih;
    boxes[o+3] = (x + ww/2.0f)*iw;

    conf2[cidx] = sigf(tc);
}

// ------- scan pass: histogram (+optional byte-bin cache), 4 classes/block ----
template<bool WRITEB>
__global__ __launch_bounds__(256, 4)
void scan_kernel(const float* __restrict__ f0, const float* __restrict__ f1,
                 const float* __restrict__ f2, const float* __restrict__ conf2,
                 unsigned int* __restrict__ ghist, unsigned char* __restrict__ binb)
{
    int cg = blockIdx.x, b = blockIdx.y, z = blockIdx.z, tid = threadIdx.x;
    int c0 = cg*4;
    int bc0 = b*NCLS + c0;
    __shared__ unsigned int h[4][256];
    h[0][tid]=0; h[1][tid]=0; h[2][tid]=0; h[3][tid]=0;
    __syncthreads();
    Seg sg = segdec(z, f0, f1, f2);
    const int P = sg.P, qc = sg.qc;
    const float* cfp = conf2 + (size_t)b*TPAD + sg.confb;
    const float* prb = sg.fbase + ((size_t)b*255 + sg.a*85 + 5 + c0)*(size_t)P + sg.lqoff*4;

    int lqA = tid, lqB = tid + 256;
    bool vA = lqA < qc, vB = lqB < qc;
    float4 cfA, cfB, A0, A1, A2, A3, B0, B1, B2, B3;
    if (vA){
        const float* pA = prb + lqA*4;
        cfA = *(const float4*)(cfp + lqA*4);
        A0 = *(const float4*)pA;         A1 = *(const float4*)(pA + P);
        A2 = *(const float4*)(pA + 2*P); A3 = *(const float4*)(pA + 3*P);
    }
    if (vB){
        const float* pB = prb + lqB*4;
        cfB = *(const float4*)(cfp + lqB*4);
        B0 = *(const float4*)pB;         B1 = *(const float4*)(pB + P);
        B2 = *(const float4*)(pB + 2*P); B3 = *(const float4*)(pB + 3*P);
    }
#define HQUAD(cls, Q, CF, LQ) { \
    float s0 = CF.x*sigf(Q.x), s1 = CF.y*sigf(Q.y), s2 = CF.z*sigf(Q.z), s3 = CF.w*sigf(Q.w); \
    int b0 = BIN_OF(s0), b1 = BIN_OF(s1), b2 = BIN_OF(s2), b3 = BIN_OF(s3); \
    bool k0 = s0 > 0.3f, k1 = s1 > 0.3f, k2 = s2 > 0.3f, k3 = s3 > 0.3f; \
    if (k0) atomicAdd(&h[cls][b0], 1u); \
    if (k1) atomicAdd(&h[cls][b1], 1u); \
    if (k2) atomicAdd(&h[cls][b2], 1u); \
    if (k3) atomicAdd(&h[cls][b3], 1u); \
    if (WRITEB){ \
        unsigned ub = (k0 ? (unsigned)(b0+1) : 0u) | ((k1 ? (unsigned)(b1+1) : 0u)<<8) \
                    | ((k2 ? (unsigned)(b2+1) : 0u)<<16) | ((k3 ? (unsigned)(b3+1) : 0u)<<24); \
        *(unsigned*)(binb + (size_t)(bc0+cls)*TPAD + sg.confb + (LQ)*4) = ub; } }
    if (vA){
        if (lqA == sg.tailq){
            A0.y=A0.z=A0.w=-INFINITY; A1.y=A1.z=A1.w=-INFINITY;
            A2.y=A2.z=A2.w=-INFINITY; A3.y=A3.z=A3.w=-INFINITY;
        }
        HQUAD(0, A0, cfA, lqA) HQUAD(1, A1, cfA, lqA) HQUAD(2, A2, cfA, lqA) HQUAD(3, A3, cfA, lqA)
    }
    if (vB){
        HQUAD(0, B0, cfB, lqB) HQUAD(1, B1, cfB, lqB) HQUAD(2, B2, cfB, lqB) HQUAD(3, B3, cfB, lqB)
    }
#undef HQUAD
    __syncthreads();
    size_t hb = ((size_t)bc0)*256 + tid;
    if (h[0][tid]) atomicAdd(&ghist[hb      ], h[0][tid]);
    if (h[1][tid]) atomicAdd(&ghist[hb + 256], h[1][tid]);
    if (h[2][tid]) atomicAdd(&ghist[hb + 512], h[2][tid]);
    if (h[3][tid]) atomicAdd(&ghist[hb + 768], h[3][tid]);
}

// ---------------- threshold-bin per (b,c) ----------------
__global__ __launch_bounds__(256)
void tb_kernel(const unsigned int* __restrict__ ghist, int* __restrict__ tb)
{
    int bc = blockIdx.x, tid = threadIdx.x;
    __shared__ int sufA[256], sufB[256];
    __shared__ int TbS;
    if (tid == 0) TbS = 0;
    sufA[tid] = (int)ghist[(size_t)bc*256 + tid];
    __syncthreads();
    int* cur = sufA; int* nxt = sufB;
    for (int d=1; d<256; d<<=1){
        int v = cur[tid] + ((tid+d) < 256 ? cur[tid+d] : 0);
        nxt[tid] = v;
        __syncthreads();
        int* t_ = cur; cur = nxt; nxt = t_;
    }
    if (cur[tid] >= TOPK && (tid == 255 || cur[tid+1] < TOPK)) TbS = tid;
    __syncthreads();
    if (tid == 0) tb[bc] = TbS;
}

// ------- compact2: scan byte-bin cache, recompute score only for survivors ---
__global__ __launch_bounds__(256, 4)
void compact2_kernel(const float* __restrict__ f0, const float* __restrict__ f1,
                     const float* __restrict__ f2, const float* __restrict__ conf2,
                     const unsigned char* __restrict__ binb,
                     const int* __restrict__ tb, int* __restrict__ gcnt,
                     float* __restrict__ gsc, int* __restrict__ gix)
{
    int cg = blockIdx.x, b = blockIdx.y, z = blockIdx.z, tid = threadIdx.x;
    int c0 = cg*4;
    int bc0 = b*NCLS + c0;
    int t0 = tb[bc0], t1 = tb[bc0+1], t2 = tb[bc0+2], t3 = tb[bc0+3];
    Seg sg = segdec(z, f0, f1, f2);
    const int P = sg.P, qc = sg.qc;
    const unsigned char* bbase = binb + sg.confb;

    int lqA = tid, lqB = tid + 256;
    bool vA = lqA < qc, vB = lqB < qc;
    unsigned uA0=0,uA1=0,uA2=0,uA3=0, uB0=0,uB1=0,uB2=0,uB3=0;
    if (vA){
        const unsigned char* pA = bbase + lqA*4;
        uA0 = *(const unsigned*)(pA + (size_t)(bc0  )*TPAD);
        uA1 = *(const unsigned*)(pA + (size_t)(bc0+1)*TPAD);
        uA2 = *(const unsigned*)(pA + (size_t)(bc0+2)*TPAD);
        uA3 = *(const unsigned*)(pA + (size_t)(bc0+3)*TPAD);
    }
    if (vB){
        const unsigned char* pB = bbase + lqB*4;
        uB0 = *(const unsigned*)(pB + (size_t)(bc0  )*TPAD);
        uB1 = *(const unsigned*)(pB + (size_t)(bc0+1)*TPAD);
        uB2 = *(const unsigned*)(pB + (size_t)(bc0+2)*TPAD);
        uB3 = *(const unsigned*)(pB + (size_t)(bc0+3)*TPAD);
    }
#define CWORD(cls, U, TX, LQ) if (U){ \
    for (int j=0; j<4; j++){ \
        unsigned bj = (U >> (8*j)) & 0xFFu; \
        if (bj && (int)bj - 1 >= (TX)){ \
            int off = sg.confb + (LQ)*4 + j; \
            float cf = conf2[(size_t)b*TPAD + off]; \
            int p = (sg.lqoff + (LQ))*4 + j; \
            float pv = sg.fbase[((size_t)b*255 + sg.a*85 + 5 + c0 + cls)*(size_t)P + p]; \
            float sc = cf * sigf(pv); \
            int pos = atomicAdd(&gcnt[bc0+cls], 1); \
            if (pos < CAP){ \
                gsc[(size_t)(bc0+cls)*CAP + pos] = sc; \
                gix[(size_t)(bc0+cls)*CAP + pos] = sg.nb + 3*p; } } } }
    if (vA){
        CWORD(0, uA0, t0, lqA) CWORD(1, uA1, t1, lqA) CWORD(2, uA2, t2, lqA) CWORD(3, uA3, t3, lqA)
    }
    if (vB){
        CWORD(0, uB0, t0, lqB) CWORD(1, uB1, t1, lqB) CWORD(2, uB2, t2, lqB) CWORD(3, uB3, t3, lqB)
    }
#undef CWORD
}

// ------- fallback compact (full rescan) if workspace too small ---------------
__global__ __launch_bounds__(256, 4)
void compact_kernel(const float* __restrict__ f0, const float* __restrict__ f1,
                    const float* __restrict__ f2, const float* __restrict__ conf2,
                    const int* __restrict__ tb, int* __restrict__ gcnt,
                    float* __restrict__ gsc, int* __restrict__ gix)
{
    int cg = blockIdx.x, b = blockIdx.y, z = blockIdx.z, tid = threadIdx.x;
    int c0 = cg*4;
    int bc0 = b*NCLS + c0;
    int t0 = tb[bc0], t1 = tb[bc0+1], t2 = tb[bc0+2], t3 = tb[bc0+3];
    Seg sg = segdec(z, f0, f1, f2);
    const int P = sg.P, qc = sg.qc;
    const float* cfp = conf2 + (size_t)b*TPAD + sg.confb;
    const float* prb = sg.fbase + ((size_t)b*255 + sg.a*85 + 5 + c0)*(size_t)P + sg.lqoff*4;

    int lqA = tid, lqB = tid + 256;
    bool vA = lqA < qc, vB = lqB < qc;
    float4 cfA, cfB, A0, A1, A2, A3, B0, B1, B2, B3;
    if (vA){
        const float* pA = prb + lqA*4;
        cfA = *(const float4*)(cfp + lqA*4);
        A0 = *(const float4*)pA;         A1 = *(const float4*)(pA + P);
        A2 = *(const float4*)(pA + 2*P); A3 = *(const float4*)(pA + 3*P);
    }
    if (vB){
        const float* pB = prb + lqB*4;
        cfB = *(const float4*)(cfp + lqB*4);
        B0 = *(const float4*)pB;         B1 = *(const float4*)(pB + P);
        B2 = *(const float4*)(pB + 2*P); B3 = *(const float4*)(pB + 3*P);
    }
#define DOJ(cls, TX, SC, IDX) { \
    if ((SC) > 0.3f){ int bin = BIN_OF(SC); \
        if (bin >= (TX)){ \
            int pos = atomicAdd(&gcnt[bc0+cls], 1); \
            if (pos < CAP){ \
                gsc[(size_t)(bc0+cls)*CAP + pos] = (SC); \
                gix[(size_t)(bc0+cls)*CAP + pos] = (IDX); } } } }
#define CQUAD(cls, Q, CF, TX, PBASE) { \
    float s0 = CF.x*sigf(Q.x), s1 = CF.y*sigf(Q.y), s2 = CF.z*sigf(Q.z), s3 = CF.w*sigf(Q.w); \
    DOJ(cls, TX, s0, sg.nb + 3*((PBASE)+0)) \
    DOJ(cls, TX, s1, sg.nb + 3*((PBASE)+1)) \
    DOJ(cls, TX, s2, sg.nb + 3*((PBASE)+2)) \
    DOJ(cls, TX, s3, sg.nb + 3*((PBASE)+3)) }
    if (vA){
        if (lqA == sg.tailq){
            A0.y=A0.z=A0.w=-INFINITY; A1.y=A1.z=A1.w=-INFINITY;
            A2.y=A2.z=A2.w=-INFINITY; A3.y=A3.z=A3.w=-INFINITY;
        }
        int pbase = (sg.lqoff + lqA)*4;
        CQUAD(0, A0, cfA, t0, pbase) CQUAD(1, A1, cfA, t1, pbase)
        CQUAD(2, A2, cfA, t2, pbase) CQUAD(3, A3, cfA, t3, pbase)
    }
    if (vB){
        int pbase = (sg.lqoff + lqB)*4;
        CQUAD(0, B0, cfB, t0, pbase) CQUAD(1, B1, cfB, t1, pbase)
        CQUAD(2, B2, cfB, t2, pbase) CQUAD(3, B3, cfB, t3, pbase)
    }
#undef CQUAD
#undef DOJ
}

// ---------------- per-(b,c): sort candidates + NMS + write out --------------
__global__ __launch_bounds__(256)
void sortnms_kernel(const float* __restrict__ gsc, const int* __restrict__ gix,
                    const int* __restrict__ gcnt, const float* __restrict__ boxes,
                    float* __restrict__ out)
{
    int c = blockIdx.x, b = blockIdx.y, tid = threadIdx.x;
    int bc = b*NCLS + c;
    __shared__ float cs[CAP];
    __shared__ int   ci[CAP];
    int n = gcnt[bc]; if (n > CAP) n = CAP;
    for (int t=tid; t<CAP; t+=256){
        if (t < n){ cs[t] = gsc[(size_t)bc*CAP + t]; ci[t] = gix[(size_t)bc*CAP + t]; }
        else { cs[t] = -INFINITY; ci[t] = 0x7FFFFFFF; }
    }
    __syncthreads();
    int S = 128; while (S < n) S <<= 1;
    for (int k=2; k<=S; k<<=1){
        for (int j=k>>1; j>0; j>>=1){
            for (int t=tid; t<S; t+=256){
                int ixj = t ^ j;
                if (ixj > t){
                    float s1 = cs[t], s2 = cs[ixj];
                    int   i1 = ci[t], i2 = ci[ixj];
                    bool b2_first = (s2 > s1) || (s2 == s1 && i2 < i1);
                    bool b1_first = (s1 > s2) || (s1 == s2 && i1 < i2);
                    bool desc = ((t & k) == 0);
                    bool sw = desc ? b2_first : b1_first;
                    if (sw){ cs[t]=s2; cs[ixj]=s1; ci[t]=i2; ci[ixj]=i1; }
                }
            }
            __syncthreads();
        }
    }

    // NMS on wave 0 (shfl broadcast, no barriers)
    int w = tid >> 6, lane = tid & 63;
    if (w == 0){
        int o0 = bc*TOPK;
        int nn = n < TOPK ? n : TOPK;
        float ay1=0.f,ax1=0.f,ay2=0.f,ax2=0.f,aar=0.f,asc=0.f; int ak=0;
        float by1=0.f,bx1=0.f,by2=0.f,bx2=0.f,bar_=0.f,bsc=0.f; int bk=0;
        {
            float s = cs[lane];
            if (s > 0.3f){
                asc = s;
                size_t q = ((size_t)b*NBOX + ci[lane])*4;
                ay1=boxes[q]; ax1=boxes[q+1]; ay2=boxes[q+2]; ax2=boxes[q+3]; ak=1;
            }
            aar = (ay2-ay1)*(ax2-ax1);
        }
        if (lane + 64 < TOPK){
            float s = cs[lane+64];
            if (s > 0.3f){
                bsc = s;
                size_t q = ((size_t)b*NBOX + ci[lane+64])*4;
                by1=boxes[q]; bx1=boxes[q+1]; by2=boxes[q+2]; bx2=boxes[q+3]; bk=1;
            }
            bar_ = (by2-by1)*(bx2-bx1);
        }
        for (int i=0; i<nn; i++){
            float iy1,ix1,iy2,ix2,iar; int ik;
            if (i < 64){
                iy1=__shfl(ay1,i); ix1=__shfl(ax1,i); iy2=__shfl(ay2,i); ix2=__shfl(ax2,i);
                iar=__shfl(aar,i); ik=__shfl(ak,i);
            } else {
                int l = i - 64;
                iy1=__shfl(by1,l); ix1=__shfl(bx1,l); iy2=__shfl(by2,l); ix2=__shfl(bx2,l);
                iar=__shfl(bar_,l); ik=__shfl(bk,l);
            }
            if (ik){
                if (ak && lane > i){
                    float q1=fmaxf(iy1,ay1), q2=fmaxf(ix1,ax1);
                    float q3=fminf(iy2,ay2), q4=fminf(ix2,ax2);
                    float inter = fmaxf(q3-q1,0.0f)*fmaxf(q4-q2,0.0f);
                    float iou = inter/(iar + aar - inter + 1e-9f);
                    if (iou > 0.3f) ak = 0;
                }
                if (bk && lane + 64 > i){
                    float q1=fmaxf(iy1,by1), q2=fmaxf(ix1,bx1);
                    float q3=fminf(iy2,by2), q4=fminf(ix2,bx2);
                    float inter = fmaxf(q3-q1,0.0f)*fmaxf(q4-q2,0.0f);
                    float iou = inter/(iar + bar_ - inter + 1e-9f);
                    if (iou > 0.3f) bk = 0;
                }
            }
        }
        {
            float k = ak ? 1.0f : 0.0f;
            size_t o5 = ((size_t)(o0+lane))*5;
            out[o5+0]=ay1*k; out[o5+1]=ax1*k; out[o5+2]=ay2*k; out[o5+3]=ax2*k; out[o5+4]=asc*k;
        }
        if (lane + 64 < TOPK){
            float k = bk ? 1.0f : 0.0f;
            size_t o5 = ((size_t)(o0+lane+64))*5;
            out[o5+0]=by1*k; out[o5+1]=bx1*k; out[o5+2]=by2*k; out[o5+3]=bx2*k; out[o5+4]=bsc*k;
        }
    }
}

// -------- per-image top-50 cap via histogram select (no serial argmax) ------
__global__ __launch_bounds__(1024)
void cap_kernel(float* __restrict__ out)
{
    int b = blockIdx.x, tid = threadIdx.x;
    __shared__ unsigned int h[256];
    __shared__ int sufA[256], sufB[256];
    __shared__ float cs[512];
    __shared__ int   ci[512];
    __shared__ int cnt, T50;
    __shared__ unsigned char msk[NSLOT];
    if (tid < 256) h[tid] = 0;
    if (tid == 0){ cnt = 0; T50 = 0; }
    for (int u=tid; u<NSLOT; u+=1024) msk[u] = 0;
    __syncthreads();

    for (int u=tid; u<NSLOT; u+=1024){
        float v = out[((size_t)b*NSLOT + u)*5 + 4];
        if (v > 0.0f) atomicAdd(&h[BIN_OF(v)], 1u);
    }
    __syncthreads();

    if (tid < 256) sufA[tid] = (int)h[tid];
    __syncthreads();
    int* cur = sufA; int* nxt = sufB;
    for (int d=1; d<256; d<<=1){
        if (tid < 256) nxt[tid] = cur[tid] + ((tid+d) < 256 ? cur[tid+d] : 0);
        __syncthreads();
        int* t_ = cur; cur = nxt; nxt = t_;
    }
    if (tid < 256){
        if (cur[tid] >= 50 && (tid == 255 || cur[tid+1] < 50)) T50 = tid;
    }
    __syncthreads();
    int T = T50;

    for (int u=tid; u<NSLOT; u+=1024){
        float v = out[((size_t)b*NSLOT + u)*5 + 4];
        if (v > 0.0f && BIN_OF(v) >= T){
            int pos = atomicAdd(&cnt, 1);
            if (pos < 512){ cs[pos] = v; ci[pos] = u; }
        }
    }
    __syncthreads();
    int n = cnt; if (n > 512) n = 512;
    for (int t=tid; t<512; t+=1024){
        if (t >= n){ cs[t] = -INFINITY; ci[t] = 0x7FFFFFFF; }
    }
    __syncthreads();

    int S = 64; while (S < n) S <<= 1;
    for (int k=2; k<=S; k<<=1){
        for (int j=k>>1; j>0; j>>=1){
            for (int t=tid; t<S; t+=1024){
                int ixj = t ^ j;
                if (ixj > t){
                    float s1 = cs[t], s2 = cs[ixj];
                    int   i1 = ci[t], i2 = ci[ixj];
                    bool b2_first = (s2 > s1) || (s2 == s1 && i2 < i1);
                    bool b1_first = (s1 > s2) || (s1 == s2 && i1 < i2);
                    bool desc = ((t & k) == 0);
                    bool sw = desc ? b2_first : b1_first;
                    if (sw){ cs[t]=s2; cs[ixj]=s1; ci[t]=i2; ci[ixj]=i1; }
                }
            }
            __syncthreads();
        }
    }

    if (tid < 50 && tid < n) msk[ci[tid]] = 1;
    __syncthreads();

    for (int u=tid; u<NSLOT; u+=1024){
        size_t o5 = ((size_t)b*NSLOT + u)*5;
        float v = out[o5 + 4];
        if (v > 0.0f && !msk[u]){
            out[o5+0]=0.f; out[o5+1]=0.f; out[o5+2]=0.f; out[o5+3]=0.f; out[o5+4]=0.f;
        }
    }
}

extern "C" void kernel_launch(void* const* d_in, const int* in_sizes, int n_in,
                              void* d_out, int out_size, void* d_ws, size_t ws_size,
                              hipStream_t stream)
{
    const float* f0 = (const float*)d_in[0];
    const float* f1 = (const float*)d_in[1];
    const float* f2 = (const float*)d_in[2];
    const float* anchors = (const float*)d_in[3];
    const float* ishape  = (const float*)d_in[4];
    float* out = (float*)d_out;

    float* boxes = (float*)d_ws;                                   // 16*22743*4
    float* conf2 = boxes + (size_t)BATCH*NBOX*4;                   // 16*22752
    unsigned int* ghist = (unsigned int*)(conf2 + (size_t)BATCH*TPAD); // 1280*256
    int* gcnt = (int*)(ghist + (size_t)BATCH*NCLS*256);            // 1280 (contiguous after ghist)
    int* tb   = gcnt + BATCH*NCLS;                                 // 1280
    float* gsc = (float*)(tb + BATCH*NCLS);                        // 1280*1024
    int*   gix = (int*)(gsc + (size_t)BATCH*NCLS*CAP);             // 1280*1024
    unsigned char* binb = (unsigned char*)(gix + (size_t)BATCH*NCLS*CAP); // 16*80*22752 bytes

    size_t words = (size_t)BATCH*NBOX*4 + (size_t)BATCH*TPAD + (size_t)BATCH*NCLS*256
                 + 2*(size_t)BATCH*NCLS + 2*(size_t)BATCH*NCLS*CAP;
    size_t need = words*4 + (size_t)BATCH*NCLS*TPAD;
    bool useB = ws_size >= need;

    dim3 dgrid((TPAD + 255)/256, BATCH);
    decode_kernel<<<dgrid, 256, 0, stream>>>(f0, f1, f2, anchors, ishape,
                                             boxes, conf2, ghist);

    dim3 hgrid(NCLS/4, BATCH, NSEG);
    if (useB)
        scan_kernel<true><<<hgrid, 256, 0, stream>>>(f0, f1, f2, conf2, ghist, binb);
    else
        scan_kernel<false><<<hgrid, 256, 0, stream>>>(f0, f1, f2, conf2, ghist, binb);

    tb_kernel<<<BATCH*NCLS, 256, 0, stream>>>(ghist, tb);

    if (useB)
        compact2_kernel<<<hgrid, 256, 0, stream>>>(f0, f1, f2, conf2, binb, tb, gcnt, gsc, gix);
    else
        compact_kernel<<<hgrid, 256, 0, stream>>>(f0, f1, f2, conf2, tb, gcnt, gsc, gix);

    dim3 sgrid(NCLS, BATCH);
    sortnms_kernel<<<sgrid, 256, 0, stream>>>(gsc, gix, gcnt, boxes, out);

    cap_kernel<<<BATCH, 1024, 0, stream>>>(out);
}